// Round 5
// baseline (1358.819 us; speedup 1.0000x reference)
//
#include <hip/hip_runtime.h>
#include <stdint.h>

// LSTM over N=512*321 independent univariate sequences, H=16, S=336, + FC(96).
// One wave = TWO independent 16-seq tiles (32 seqs) -> two interleaved
// recurrence chains per instruction stream to hide LDS/MFMA latency.
// Per tile per step: 4x mfma_f32_16x16x32_f16 computes pre[64 gates][16 seqs]
// in TABLE-INDEX SPACE (scale+offset folded into f16 A weights + fp32 C bias).
// Activations = LDS lerp-table lookups (sigma/tanh, 1024 x (value,slope)).
// State in registers; h transpose via ds_bpermute shuffles. Weights/bias/FC
// fragments shared across both tiles.

typedef _Float16 half8 __attribute__((ext_vector_type(8)));
typedef float floatx4 __attribute__((ext_vector_type(4)));

#define HH 16
#define SS 336
#define CCD 321
#define BBD 512
#define PPD 96
#define NSEQ (BBD * CCD)       // 164352
#define NTILES (NSEQ / 16)     // 10272
#define TPW 2                  // tiles per wave

#define TABN 1024
#define SIG_SCALE 64.0f        // 1024/16 -> sigma domain [-8, 8]
#define TANH_SCALE 128.0f      // 1024/8  -> tanh  domain [-4, 4]
#define IDX_OFF 512.0f
#define IDX_MAX 1022.995f      // clamp so i+1 (slope endpoint) stays in range

static_assert(NSEQ % 16 == 0, "tile exactness");
static_assert(NTILES % (4 * TPW) == 0, "block exactness");  // 10272 / 8 = 1284

union U32H2 { uint32_t u; _Float16 h[2]; };
union BFrag { uint32_t u[4]; half8 v; };

// clamp + split + lerp from a (value, slope) table. y already in index space.
__device__ __forceinline__ float lut(const float2* __restrict__ tab, float y) {
    y = __builtin_amdgcn_fmed3f(y, 0.0f, IDX_MAX);   // clamp (saturation)
    float fr = __builtin_amdgcn_fractf(y);           // y - floor(y), y >= 0
    int i = (int)y;                                  // trunc == floor, y >= 0
    float2 e = tab[i];                               // ds_read_b64
    return fmaf(fr, e.y, e.x);                       // value + fr * slope
}

__global__ __launch_bounds__(256) void lstm_fused(
    const float* __restrict__ x,      // [B,S,C]
    const float* __restrict__ W_ih,   // [64,1]
    const float* __restrict__ W_hh,   // [64,16]
    const float* __restrict__ b_ih,   // [64]
    const float* __restrict__ b_hh,   // [64]
    const float* __restrict__ W_fc,   // [96,16]
    const float* __restrict__ b_fc,   // [96]
    float* __restrict__ out)          // [B,96,C]
{
    __shared__ float2 sig_tab[TABN];
    __shared__ float2 tanh_tab[TABN];

    // ---- build activation tables (accurate libm, once per block) ----
    for (int i = (int)threadIdx.x; i < TABN; i += 256) {
        float x0 = ((float)i       - IDX_OFF) / SIG_SCALE;
        float x1 = ((float)(i + 1) - IDX_OFF) / SIG_SCALE;
        float s0 = 1.0f / (1.0f + expf(-x0));
        float s1 = 1.0f / (1.0f + expf(-x1));
        sig_tab[i] = make_float2(s0, s1 - s0);
        float u0 = ((float)i       - IDX_OFF) / TANH_SCALE;
        float u1 = ((float)(i + 1) - IDX_OFF) / TANH_SCALE;
        float t0 = tanhf(u0);
        float t1 = tanhf(u1);
        tanh_tab[i] = make_float2(t0, t1 - t0);
    }
    __syncthreads();

    const int lane = (int)(threadIdx.x & 63u);
    const int wid  = (int)(threadIdx.x >> 6u);
    const int tile0 = ((int)blockIdx.x * 4 + wid) * TPW;

    const int n16 = lane & 15;   // sequence within tile (B col / D col / A row)
    const int g   = lane >> 4;   // k-group (A/B), row-group (C/D)

    // i,f,o use sigma table (scale 64); g uses tanh table (scale 128)
    const float gate_scale[4] = { SIG_SCALE, SIG_SCALE, TANH_SCALE, SIG_SCALE };

    // ---- A fragments (shared by both tiles): S_t * W'[j][k]
    half8 a_frag[4];
    #pragma unroll
    for (int t = 0; t < 4; ++t) {
        const int j = t * 16 + n16;
        const float sc = gate_scale[t];
        #pragma unroll
        for (int i = 0; i < 8; ++i) {
            const int k = g * 8 + i;
            float w = 0.0f;
            if (k < 16)       w = W_hh[j * 16 + k];
            else if (k == 16) w = W_ih[j];
            a_frag[t][i] = (_Float16)(w * sc);
        }
    }
    // ---- bias via C operand (exact fp32, index space): S_t * b + 512
    floatx4 bias_frag[4];
    #pragma unroll
    for (int t = 0; t < 4; ++t) {
        #pragma unroll
        for (int r = 0; r < 4; ++r) {
            const int j = t * 16 + g * 4 + r;
            bias_frag[t][r] = (b_ih[j] + b_hh[j]) * gate_scale[t] + IDX_OFF;
        }
    }

    // shuffle selectors: lane (n16,g) pulls h-packs from lanes (n16,2g),(n16,2g+1)
    const int selA = n16 + ((g << 5) & 63);
    const int selB = selA + 16;

    // ---- per-tile recurrent state ----
    uint32_t hv0[TPW], hv1[TPW];
    float cst[TPW][4];
    const float* xptr[TPW];
    float xcur[TPW];
    #pragma unroll
    for (int tt = 0; tt < TPW; ++tt) {
        hv0[tt] = 0u; hv1[tt] = 0u;
        #pragma unroll
        for (int r = 0; r < 4; ++r) cst[tt][r] = 0.0f;
        const int n = (tile0 + tt) * 16 + n16;
        const int b = n / CCD;
        const int c = n - b * CCD;
        xptr[tt] = x + (size_t)b * (SS * CCD) + c;
        xcur[tt] = xptr[tt][0];
    }

    for (int s = 0; s < SS; ++s) {
        float xnext[TPW];
        #pragma unroll
        for (int tt = 0; tt < TPW; ++tt)
            xnext[tt] = (s + 1 < SS) ? xptr[tt][(s + 1) * CCD] : 0.0f;

        // rebuild B fragments (h_aug columns) for both tiles
        BFrag bf[TPW];
        #pragma unroll
        for (int tt = 0; tt < TPW; ++tt) {
            uint32_t s0 = (uint32_t)__shfl((int)hv0[tt], selA, 64);
            uint32_t s1 = (uint32_t)__shfl((int)hv1[tt], selA, 64);
            uint32_t s2 = (uint32_t)__shfl((int)hv0[tt], selB, 64);
            uint32_t s3 = (uint32_t)__shfl((int)hv1[tt], selB, 64);
            U32H2 xp; xp.h[0] = (_Float16)xcur[tt]; xp.h[1] = (_Float16)0.0f;
            bf[tt].u[0] = (g < 2) ? s0 : ((g == 2) ? xp.u : 0u);
            bf[tt].u[1] = (g < 2) ? s1 : 0u;
            bf[tt].u[2] = (g < 2) ? s2 : 0u;
            bf[tt].u[3] = (g < 2) ? s3 : 0u;
        }

        // pre-activations in table-index space, both tiles (8 MFMA)
        floatx4 acc[TPW][4];
        #pragma unroll
        for (int t = 0; t < 4; ++t) {
            #pragma unroll
            for (int tt = 0; tt < TPW; ++tt)
                acc[tt][t] = __builtin_amdgcn_mfma_f32_16x16x32_f16(
                    a_frag[t], bf[tt].v, bias_frag[t], 0, 0, 0);
        }

        // gates + state update, both tiles interleaved by the scheduler
        #pragma unroll
        for (int tt = 0; tt < TPW; ++tt) {
            float hn[4];
            #pragma unroll
            for (int r = 0; r < 4; ++r) {
                float iv = lut(sig_tab,  acc[tt][0][r]);
                float fv = lut(sig_tab,  acc[tt][1][r]);
                float gv = lut(tanh_tab, acc[tt][2][r]);
                float ov = lut(sig_tab,  acc[tt][3][r]);
                float cc = fmaf(fv, cst[tt][r], iv * gv);
                cst[tt][r] = cc;
                float tc = lut(tanh_tab, fmaf(cc, TANH_SCALE, IDX_OFF));
                hn[r] = ov * tc;
            }
            U32H2 p0, p1;
            p0.h[0] = (_Float16)hn[0]; p0.h[1] = (_Float16)hn[1];
            p1.h[0] = (_Float16)hn[2]; p1.h[1] = (_Float16)hn[3];
            hv0[tt] = p0.u; hv1[tt] = p1.u;
            xcur[tt] = xnext[tt];
        }
    }

    // ---- FC head: pred[p][n] = W_fc @ h_last + b_fc; weights shared ----
    BFrag bfc[TPW];
    #pragma unroll
    for (int tt = 0; tt < TPW; ++tt) {
        uint32_t s0 = (uint32_t)__shfl((int)hv0[tt], selA, 64);
        uint32_t s1 = (uint32_t)__shfl((int)hv1[tt], selA, 64);
        uint32_t s2 = (uint32_t)__shfl((int)hv0[tt], selB, 64);
        uint32_t s3 = (uint32_t)__shfl((int)hv1[tt], selB, 64);
        bfc[tt].u[0] = (g < 2) ? s0 : 0u;
        bfc[tt].u[1] = (g < 2) ? s1 : 0u;
        bfc[tt].u[2] = (g < 2) ? s2 : 0u;
        bfc[tt].u[3] = (g < 2) ? s3 : 0u;
    }

    #pragma unroll
    for (int t = 0; t < 6; ++t) {
        half8 afc;
        #pragma unroll
        for (int i = 0; i < 8; ++i) {
            const int k = g * 8 + i;
            float w = (k < 16) ? W_fc[(t * 16 + n16) * 16 + k] : 0.0f;
            afc[i] = (_Float16)w;
        }
        floatx4 cf;
        #pragma unroll
        for (int r = 0; r < 4; ++r) cf[r] = b_fc[t * 16 + g * 4 + r];

        #pragma unroll
        for (int tt = 0; tt < TPW; ++tt) {
            floatx4 d = __builtin_amdgcn_mfma_f32_16x16x32_f16(afc, bfc[tt].v, cf, 0, 0, 0);
            const int n = (tile0 + tt) * 16 + n16;
            const int b = n / CCD;
            const int c = n - b * CCD;
            const size_t obase = (size_t)b * (PPD * CCD) + c;
            #pragma unroll
            for (int r = 0; r < 4; ++r) {
                const int p = t * 16 + g * 4 + r;
                out[obase + (size_t)p * CCD] = d[r];
            }
        }
    }
}

extern "C" void kernel_launch(void* const* d_in, const int* in_sizes, int n_in,
                              void* d_out, int out_size, void* d_ws, size_t ws_size,
                              hipStream_t stream) {
    const float* x    = (const float*)d_in[0];
    const float* W_ih = (const float*)d_in[1];
    const float* W_hh = (const float*)d_in[2];
    const float* b_ih = (const float*)d_in[3];
    const float* b_hh = (const float*)d_in[4];
    const float* W_fc = (const float*)d_in[5];
    const float* b_fc = (const float*)d_in[6];
    float* out = (float*)d_out;

    dim3 grid(NTILES / (4 * TPW));   // 1284 blocks
    dim3 block(256);                 // 4 waves/block, 2 tiles (32 seqs) per wave
    hipLaunchKernelGGL(lstm_fused, grid, block, 0, stream,
                       x, W_ih, W_hh, b_ih, b_hh, W_fc, b_fc, out);
}

// Round 7
// 1198.945 us; speedup vs baseline: 1.1333x; 1.1333x over previous
//
#include <hip/hip_runtime.h>
#include <stdint.h>

// LSTM over N=512*321 independent univariate sequences, H=16, S=336, + FC(96).
// One wave = one 16-seq tile (TPW=1: R5 showed TLP > ILP here).
// Per step: 4x mfma_f32_16x16x32_f16 computes pre[64 gates][16 seqs] directly
// in TABLE-INDEX SPACE (scale + offset + 0.5 rounding folded into f16 A
// weights and fp32 C bias). Activations = nearest-neighbor LDS lookups in
// 4096-entry f32 tables (sigma/tanh): fmed3 + cvt + addr + ds_read_b32 =
// 3 VALU + 1 b32 gather per activation (vs lerp's 5 VALU + b64 gather).
// State in registers; h transpose via 4 ds_bpermute shuffles.

typedef _Float16 half8 __attribute__((ext_vector_type(8)));
typedef float floatx4 __attribute__((ext_vector_type(4)));

#define HH 16
#define SS 336
#define CCD 321
#define BBD 512
#define PPD 96
#define NSEQ (BBD * CCD)       // 164352
#define NTILES (NSEQ / 16)     // 10272, exact

#define TABN 4096
#define SIG_SCALE 256.0f       // 4096/16 -> sigma domain [-8, 8]
#define TANH_SCALE 512.0f      // 4096/8  -> tanh  domain [-4, 4]
#define IDX_OFF 2048.5f        // center offset + 0.5 (trunc -> round)
#define IDX_MAXF 4095.0f

static_assert(NSEQ % 16 == 0, "tile exactness");
static_assert(NTILES % 4 == 0, "block exactness");

union U32H2 { uint32_t u; _Float16 h[2]; };
union BFrag { uint32_t u[4]; half8 v; };

// nearest-neighbor lookup; y already in index space (incl. +0.5 rounding)
__device__ __forceinline__ float lut(const float* __restrict__ tab, float y) {
    y = __builtin_amdgcn_fmed3f(y, 0.0f, IDX_MAXF);  // clamp (saturation)
    return tab[(int)y];                              // trunc == round(orig)
}

__global__ __launch_bounds__(256) void lstm_fused(
    const float* __restrict__ x,      // [B,S,C]
    const float* __restrict__ W_ih,   // [64,1]
    const float* __restrict__ W_hh,   // [64,16]
    const float* __restrict__ b_ih,   // [64]
    const float* __restrict__ b_hh,   // [64]
    const float* __restrict__ W_fc,   // [96,16]
    const float* __restrict__ b_fc,   // [96]
    float* __restrict__ out)          // [B,96,C]
{
    __shared__ float sig_tab[TABN];
    __shared__ float tanh_tab[TABN];

    // ---- build activation tables (accurate libm, once per block) ----
    for (int i = (int)threadIdx.x; i < TABN; i += 256) {
        float xs = ((float)i - 2048.0f) / SIG_SCALE;
        sig_tab[i] = 1.0f / (1.0f + expf(-xs));
        float xt = ((float)i - 2048.0f) / TANH_SCALE;
        tanh_tab[i] = tanhf(xt);
    }
    __syncthreads();

    const int lane = (int)(threadIdx.x & 63u);
    const int wid  = (int)(threadIdx.x >> 6u);
    const int tile = (int)blockIdx.x * 4 + wid;
    if (tile >= NTILES) return;

    const int n16 = lane & 15;   // sequence within tile (B col / D col / A row)
    const int g   = lane >> 4;   // k-group (A/B), row-group (C/D)

    const int n = tile * 16 + n16;       // global sequence id = b*C + c
    const int b = n / CCD;
    const int c = n - b * CCD;

    // i,f,o use sigma table (scale 256); g uses tanh table (scale 512)
    const float gate_scale[4] = { SIG_SCALE, SIG_SCALE, TANH_SCALE, SIG_SCALE };

    // ---- A fragments: S_t * W'[j][k]; j = gate unit, k = g*8 + i;
    //      k<16 -> W_hh, k==16 -> W_ih, else 0. f16.
    half8 a_frag[4];
    #pragma unroll
    for (int t = 0; t < 4; ++t) {
        const int j = t * 16 + n16;
        const float sc = gate_scale[t];
        #pragma unroll
        for (int i = 0; i < 8; ++i) {
            const int k = g * 8 + i;
            float w = 0.0f;
            if (k < 16)       w = W_hh[j * 16 + k];
            else if (k == 16) w = W_ih[j];
            a_frag[t][i] = (_Float16)(w * sc);
        }
    }
    // ---- bias via C operand (exact fp32, index space): S_t * b + 2048.5
    floatx4 bias_frag[4];
    #pragma unroll
    for (int t = 0; t < 4; ++t) {
        #pragma unroll
        for (int r = 0; r < 4; ++r) {
            const int j = t * 16 + g * 4 + r;
            bias_frag[t][r] = (b_ih[j] + b_hh[j]) * gate_scale[t] + IDX_OFF;
        }
    }

    // shuffle selectors: lane (n16,g) pulls h-packs from lanes (n16,2g),(n16,2g+1)
    const int selA = n16 + ((g << 5) & 63);
    const int selB = selA + 16;

    uint32_t hv0 = 0u, hv1 = 0u;   // packed f16 pairs: (h[4g],h[4g+1]), (h[4g+2],h[4g+3])
    float cst[4] = {0.f, 0.f, 0.f, 0.f};

    const float* xptr = x + (size_t)b * (SS * CCD) + c;
    float xcur = xptr[0];

    for (int s = 0; s < SS; ++s) {
        float xnext = (s + 1 < SS) ? xptr[(s + 1) * CCD] : 0.0f;

        // rebuild B fragment (h_aug columns) from previous h
        uint32_t s0 = (uint32_t)__shfl((int)hv0, selA, 64);
        uint32_t s1 = (uint32_t)__shfl((int)hv1, selA, 64);
        uint32_t s2 = (uint32_t)__shfl((int)hv0, selB, 64);
        uint32_t s3 = (uint32_t)__shfl((int)hv1, selB, 64);

        U32H2 xp; xp.h[0] = (_Float16)xcur; xp.h[1] = (_Float16)0.0f;

        BFrag bf;
        bf.u[0] = (g < 2) ? s0 : ((g == 2) ? xp.u : 0u);
        bf.u[1] = (g < 2) ? s1 : 0u;
        bf.u[2] = (g < 2) ? s2 : 0u;
        bf.u[3] = (g < 2) ? s3 : 0u;

        // pre-activations in table-index space
        floatx4 ai = __builtin_amdgcn_mfma_f32_16x16x32_f16(a_frag[0], bf.v, bias_frag[0], 0, 0, 0);
        floatx4 af = __builtin_amdgcn_mfma_f32_16x16x32_f16(a_frag[1], bf.v, bias_frag[1], 0, 0, 0);
        floatx4 ag = __builtin_amdgcn_mfma_f32_16x16x32_f16(a_frag[2], bf.v, bias_frag[2], 0, 0, 0);
        floatx4 ao = __builtin_amdgcn_mfma_f32_16x16x32_f16(a_frag[3], bf.v, bias_frag[3], 0, 0, 0);

        float hn[4];
        #pragma unroll
        for (int r = 0; r < 4; ++r) {
            float iv = lut(sig_tab,  ai[r]);
            float fv = lut(sig_tab,  af[r]);
            float gv = lut(tanh_tab, ag[r]);
            float ov = lut(sig_tab,  ao[r]);
            float cc = fmaf(fv, cst[r], iv * gv);
            cst[r] = cc;
            float tc = lut(tanh_tab, fmaf(cc, TANH_SCALE, IDX_OFF));
            hn[r] = ov * tc;
        }

        U32H2 p0, p1;
        p0.h[0] = (_Float16)hn[0]; p0.h[1] = (_Float16)hn[1];
        p1.h[0] = (_Float16)hn[2]; p1.h[1] = (_Float16)hn[3];
        hv0 = p0.u; hv1 = p1.u;
        xcur = xnext;
    }

    // ---- FC head: pred[p][n] = W_fc @ h_last + b_fc, 6 tiles of 16 rows
    uint32_t s0 = (uint32_t)__shfl((int)hv0, selA, 64);
    uint32_t s1 = (uint32_t)__shfl((int)hv1, selA, 64);
    uint32_t s2 = (uint32_t)__shfl((int)hv0, selB, 64);
    uint32_t s3 = (uint32_t)__shfl((int)hv1, selB, 64);

    BFrag bfc;
    bfc.u[0] = (g < 2) ? s0 : 0u;
    bfc.u[1] = (g < 2) ? s1 : 0u;
    bfc.u[2] = (g < 2) ? s2 : 0u;
    bfc.u[3] = (g < 2) ? s3 : 0u;

    const size_t obase = (size_t)b * (PPD * CCD) + c;
    #pragma unroll
    for (int t = 0; t < 6; ++t) {
        half8 afc;
        #pragma unroll
        for (int i = 0; i < 8; ++i) {
            const int k = g * 8 + i;
            float w = (k < 16) ? W_fc[(t * 16 + n16) * 16 + k] : 0.0f;
            afc[i] = (_Float16)w;
        }
        floatx4 cf;
        #pragma unroll
        for (int r = 0; r < 4; ++r) cf[r] = b_fc[t * 16 + g * 4 + r];

        floatx4 d = __builtin_amdgcn_mfma_f32_16x16x32_f16(afc, bfc.v, cf, 0, 0, 0);

        #pragma unroll
        for (int r = 0; r < 4; ++r) {
            const int p = t * 16 + g * 4 + r;
            out[obase + (size_t)p * CCD] = d[r];
        }
    }
}

extern "C" void kernel_launch(void* const* d_in, const int* in_sizes, int n_in,
                              void* d_out, int out_size, void* d_ws, size_t ws_size,
                              hipStream_t stream) {
    const float* x    = (const float*)d_in[0];
    const float* W_ih = (const float*)d_in[1];
    const float* W_hh = (const float*)d_in[2];
    const float* b_ih = (const float*)d_in[3];
    const float* b_hh = (const float*)d_in[4];
    const float* W_fc = (const float*)d_in[5];
    const float* b_fc = (const float*)d_in[6];
    float* out = (float*)d_out;

    dim3 grid(NTILES / 4);   // 2568 blocks
    dim3 block(256);         // 4 waves/block, 1 tile (16 seqs) per wave
    hipLaunchKernelGGL(lstm_fused, grid, block, 0, stream,
                       x, W_ih, W_hh, b_ih, b_hh, W_fc, b_fc, out);
}